// Round 13
// baseline (73.386 us; speedup 1.0000x reference)
//
#include <hip/hip_runtime.h>
#include <hip/hip_fp16.h>

#define HH 128
#define WW 128
#define CIN 128
#define COUT 256
#define K9 9
#define HW (HH*WW)          // 16384
#define PIX (2*HW)          // 32768
#define KDIM (CIN*K9)       // 1152
#define BN_EPS 1e-5f

typedef __attribute__((ext_vector_type(8))) short short8;
typedef __attribute__((ext_vector_type(4))) float f32x4;
typedef _Float16 half8 __attribute__((ext_vector_type(8)));
typedef unsigned short u16;
typedef unsigned int u32;

union H8 { short8 s; __half2 h2[4]; half8 h; };

// 16B sampling metadata: 4 clamped hw-indices (u16) + 4 premultiplied bilinear
// weights (f16, mask & validity folded in). Lives in LDS only.
struct __align__(16) Meta16 { ushort4 idx; __half2 w01, w23; };
static_assert(sizeof(Meta16) == 16, "");

__device__ __forceinline__ u16 f2h(float f) {
    union { __half h; u16 u; } x; x.h = __float2half_rn(f); return x.u;
}

// ---------------------------------------------------------------------------
// prep_xt: x [B][C][HW] f32  ->  xt [B][HW][C] f16 (NHWC). LDS transpose.
// ---------------------------------------------------------------------------
__global__ __launch_bounds__(256) void prep_xt(const float* __restrict__ x,
                                               u16* __restrict__ xt) {
    __shared__ float tile[32][129];
    const int b   = blockIdx.y;
    const int hw0 = blockIdx.x * 32;
    const float* __restrict__ xb = x + (size_t)b * (CIN*HW);
    #pragma unroll
    for (int i = 0; i < 16; ++i) {
        const int idx = threadIdx.x + i*256;
        const int c = idx >> 5, hwl = idx & 31;
        tile[hwl][c] = xb[(size_t)c*HW + hw0 + hwl];
    }
    __syncthreads();
    const int hwl = threadIdx.x >> 3;
    const int c0  = (threadIdx.x & 7) * 16;
    short8 s0, s1;
    #pragma unroll
    for (int j = 0; j < 8; ++j) {
        s0[j] = (short)f2h(tile[hwl][c0 + j]);
        s1[j] = (short)f2h(tile[hwl][c0 + 8 + j]);
    }
    u16* dst = xt + ((size_t)b*HW + hw0 + hwl)*CIN + c0;
    *(short8*)dst = s0;
    *(short8*)(dst + 8) = s1;
}

// ---------------------------------------------------------------------------
// prep_wall: f16 sub-tile-major weight layouts.
//   wT2    [tt][o(256)][32ch]   (tt = k*4+s)
//   wOffT2 [tt][j(32)][32ch]    (j>=27 zero-padded)
// ---------------------------------------------------------------------------
__global__ __launch_bounds__(128) void prep_wall(const float* __restrict__ w_dcn,
                                                 const float* __restrict__ w_off,
                                                 u16* __restrict__ wT2,
                                                 u16* __restrict__ wOffT2) {
    const int c = threadIdx.x;             // 0..127
    const int k = blockIdx.x;              // 0..8
    const int o = blockIdx.y;              // 0..287
    const int s = c >> 5, ch = c & 31;
    const int tt = k*4 + s;
    if (o < COUT) {
        wT2[((size_t)tt*COUT + o)*32 + ch] = f2h(w_dcn[(size_t)o*KDIM + c*K9 + k]);
    } else {
        const int j = o - COUT;
        wOffT2[((size_t)tt*32 + j)*32 + ch] =
            (j < 27) ? f2h(w_off[(size_t)j*KDIM + c*K9 + k]) : (u16)0;
    }
}

// ---------------------------------------------------------------------------
// dcn_fused: offs-conv (MFMA, meta->LDS) + LDS-staged implicit GEMM.
// 512 threads = 8 waves per block, 64 px per block, TWO blocks per CU:
// independent blocks overlap (one block's barrier drain hides under the
// other's MFMA/gather work). Wave wv owns o-slice [wv*32,+32) x all 64 px.
// Vs double-buffered (2x16KB) -> ONE barrier per phase (MFMA reads Vs[cur]
// while combine writes Vs[cur^1]). FIFO-correct: A-frags first, gathers
// second, counted vmcnt at MFMAs keeps gathers in flight.
// ---------------------------------------------------------------------------
__global__ __launch_bounds__(512, 4) __attribute__((amdgpu_waves_per_eu(4, 4)))
void dcn_fused(
    const u16* __restrict__ xt, const u16* __restrict__ wT2,
    const u16* __restrict__ wOffT2, const float* __restrict__ b_off,
    const float* __restrict__ b_dcn, const float* __restrict__ gamma,
    const float* __restrict__ beta, const float* __restrict__ mmean,
    const float* __restrict__ mvar, float* __restrict__ out)
{
    __shared__ __align__(16) u16 Vs[2][64*128];      // 2 x 16 KB
    __shared__ __align__(16) Meta16 metaL[K9*64];    // 9216 B
    float* wiL = (float*)&Vs[0][0];                  // [64][33] f32 alias

    const int t = threadIdx.x, l = t & 63, wv = t >> 6;   // wv 0..7
    const int l15 = l & 15, lq = l >> 4;
    const int bid = (blockIdx.x & 7) * 64 + (blockIdx.x >> 3);  // 512 blocks
    const int pg0 = bid * 64;
    const int b   = pg0 >> 14;
    const int hw0 = pg0 & 16383;
    const u16* __restrict__ xtb = xt + (size_t)b * (HW*CIN);

    // ================= phase -1: offsets conv + meta build =================
    {
        const int pxg = wv >> 1;          // px group 0..3 (16 px)
        const int jh  = wv & 1;           // j half 0..1
        const int px  = pxg*16 + l15;     // 0..63
        const int pg  = pg0 + px;
        const int hw  = pg & 16383;
        const int h = hw >> 7, w = hw & 127;
        f32x4 oa = {0.f,0.f,0.f,0.f};
        #pragma unroll
        for (int tt = 0; tt < 36; ++tt) {
            const int k = tt >> 2, c0 = (tt & 3) * 32;
            const int yy = h + (k/3) - 1, xx = w + (k%3) - 1;
            const bool valid = ((unsigned)yy < HH) && ((unsigned)xx < WW);
            const int idx = min(max(yy,0),HH-1)*WW + min(max(xx,0),WW-1);
            H8 bv, av;
            bv.s = *(const short8*)(xtb + (size_t)idx*CIN + c0 + lq*8);
            av.s = *(const short8*)(wOffT2 + ((size_t)tt*32 + jh*16 + l15)*32 + lq*8);
            if (!valid) bv.s = (short8){0,0,0,0,0,0,0,0};
            oa = __builtin_amdgcn_mfma_f32_16x16x32_f16(av.h, bv.h, oa, 0,0,0);
        }
        #pragma unroll
        for (int r = 0; r < 4; ++r)
            wiL[px*33 + jh*16 + lq*4 + r] = oa[r];
        __syncthreads();

        #pragma unroll
        for (int rd = 0; rd < 2; ++rd) {
            const int u = t + rd*512;
            if (u < 576) {
                const int px2 = u & 63, k = u >> 6;
                const int hwp = (pg0 + px2) & 16383;
                const int hp = hwp >> 7, wp = hwp & 127;
                const float dy = wiL[px2*33 + 2*k]     + b_off[2*k];
                const float dx = wiL[px2*33 + 2*k + 1] + b_off[2*k+1];
                const float mm = wiL[px2*33 + 18 + k]  + b_off[18+k];
                const float py = (float)hp + (float)(k/3) - 1.0f + dy;
                const float px_ = (float)wp + (float)(k%3) - 1.0f + dx;
                const float msk = 1.0f / (1.0f + expf(-mm));
                const float y0f = floorf(py), x0f = floorf(px_);
                const float wy = py - y0f, wx = px_ - x0f;
                const int y0 = (int)y0f, x0 = (int)x0f;
                const int y1 = y0 + 1,   x1 = x0 + 1;
                const bool v00 = ((unsigned)y0 < HH) && ((unsigned)x0 < WW);
                const bool v01 = ((unsigned)y0 < HH) && ((unsigned)x1 < WW);
                const bool v10 = ((unsigned)y1 < HH) && ((unsigned)x0 < WW);
                const bool v11 = ((unsigned)y1 < HH) && ((unsigned)x1 < WW);
                const int y0c = min(max(y0,0),HH-1), y1c = min(max(y1,0),HH-1);
                const int x0c = min(max(x0,0),WW-1), x1c = min(max(x1,0),WW-1);
                Meta16 mo;
                mo.idx.x = (u16)(y0c*WW + x0c);
                mo.idx.y = (u16)(y0c*WW + x1c);
                mo.idx.z = (u16)(y1c*WW + x0c);
                mo.idx.w = (u16)(y1c*WW + x1c);
                const float f00 = v00 ? (1.f-wy)*(1.f-wx)*msk : 0.f;
                const float f01 = v01 ? (1.f-wy)*wx*msk       : 0.f;
                const float f10 = v10 ? wy*(1.f-wx)*msk       : 0.f;
                const float f11 = v11 ? wy*wx*msk             : 0.f;
                mo.w01 = __floats2half2_rn(f00, f01);
                mo.w23 = __floats2half2_rn(f10, f11);
                metaL[k*64 + px2] = mo;
            }
        }
        __syncthreads();   // metaL ready; wiL (Vs[0] alias) dead
    }

    // ================= main GEMM =================
    const int pxl  = t >> 3;           // gather px 0..63
    const int cb   = t & 7;            // gather 16B chunk 0..7
    const int px15 = pxl & 15;

    f32x4 acc[8];                      // acc[m*4+n], m<2, n<4
    #pragma unroll
    for (int i = 0; i < 8; ++i) acc[i] = (f32x4){0.f,0.f,0.f,0.f};

    const u16 *g0, *g1, *g2, *g3;
    __half2 wb0, wb1, wb2, wb3;

#define SETMETA(k_) do { \
    const Meta16 mt_ = metaL[(k_)*64 + pxl]; \
    g0 = xtb + (size_t)mt_.idx.x*CIN + cb*8; \
    g1 = xtb + (size_t)mt_.idx.y*CIN + cb*8; \
    g2 = xtb + (size_t)mt_.idx.z*CIN + cb*8; \
    g3 = xtb + (size_t)mt_.idx.w*CIN + cb*8; \
    wb0 = __half2half2(__low2half(mt_.w01)); \
    wb1 = __half2half2(__high2half(mt_.w01)); \
    wb2 = __half2half2(__low2half(mt_.w23)); \
    wb3 = __half2half2(__high2half(mt_.w23)); \
} while (0)

#define ISSUE(cr_, u_) do { \
    cr_[0].s = *(const short8*)(g0 + (u_)*64); \
    cr_[1].s = *(const short8*)(g1 + (u_)*64); \
    cr_[2].s = *(const short8*)(g2 + (u_)*64); \
    cr_[3].s = *(const short8*)(g3 + (u_)*64); \
} while (0)

#define COMBINE_WRITE(cr_, u_, buf_) do { \
    H8 r_; \
    _Pragma("unroll") \
    for (int i_ = 0; i_ < 4; ++i_) \
        r_.h2[i_] = __hfma2(cr_[3].h2[i_], wb3, __hfma2(cr_[2].h2[i_], wb2, \
                    __hfma2(cr_[1].h2[i_], wb1, __hmul2(cr_[0].h2[i_], wb0)))); \
    *(short8*)&Vs[buf_][pxl*128 + ((cb + (u_)*8) ^ px15)*8] = r_.s; \
} while (0)

    H8 cA[4], cB[4];
    // prologue: gather k=0 -> Vs[0]
    SETMETA(0);
    ISSUE(cA, 0); ISSUE(cB, 1);
    COMBINE_WRITE(cA, 0, 0); COMBINE_WRITE(cB, 1, 0);
    __syncthreads();

    int cur = 0;
    for (int k = 0; k < 9; ++k) {
        const bool pf = (k < 8);
        // A-frags for all 4 subtiles x 2 m-frags FIRST (oldest in VMEM FIFO)
        H8 av[4][2];
        #pragma unroll
        for (int s = 0; s < 4; ++s)
            #pragma unroll
            for (int m = 0; m < 2; ++m)
                av[s][m].s = *(const short8*)
                    (wT2 + ((size_t)(k*4 + s)*COUT + wv*32 + m*16 + l15)*32 + lq*8);
        __builtin_amdgcn_sched_barrier(0);
        if (pf) { SETMETA(k+1); ISSUE(cA, 0); ISSUE(cB, 1); }
        __builtin_amdgcn_sched_barrier(0);

        #pragma unroll
        for (int s = 0; s < 4; ++s) {
            #pragma unroll
            for (int nh = 0; nh < 2; ++nh) {
                // batched: 2 ds_reads in flight, then 4 MFMAs (m2 x n2)
                H8 bf[2];
                #pragma unroll
                for (int j = 0; j < 2; ++j) {
                    const int n = nh*2 + j;
                    bf[j].s = *(const short8*)
                        &Vs[cur][(n*16 + l15)*128 + ((s*4 + lq) ^ l15)*8];
                }
                #pragma unroll
                for (int m = 0; m < 2; ++m)
                    #pragma unroll
                    for (int j = 0; j < 2; ++j)
                        acc[m*4 + nh*2 + j] =
                            __builtin_amdgcn_mfma_f32_16x16x32_f16(
                                av[s][m].h, bf[j].h, acc[m*4 + nh*2 + j], 0, 0, 0);
            }
        }
        // combine k+1 into the OTHER buffer while this phase's reads are done
        // locally (per-wave ds ordering); single barrier covers both.
        if (pf) { COMBINE_WRITE(cA, 0, cur ^ 1); COMBINE_WRITE(cB, 1, cur ^ 1); }
        __syncthreads();
        cur ^= 1;
    }
#undef SETMETA
#undef ISSUE
#undef COMBINE_WRITE

    // ---- epilogue: bias + BN + ReLU, coalesced stores ----
    #pragma unroll
    for (int m = 0; m < 2; ++m) {
        #pragma unroll
        for (int r = 0; r < 4; ++r) {
            const int o = wv*32 + m*16 + lq*4 + r;
            const float sc = gamma[o] * rsqrtf(mvar[o] + BN_EPS);
            const float sh = (b_dcn[o] - mmean[o]) * sc + beta[o];
            float* __restrict__ op = out + ((size_t)(b*COUT + o) << 14) + hw0;
            #pragma unroll
            for (int n = 0; n < 4; ++n) {
                const float v = fmaf(acc[m*4 + n][r], sc, sh);
                op[n*16 + l15] = fmaxf(v, 0.f);
            }
        }
    }
}

extern "C" void kernel_launch(void* const* d_in, const int* in_sizes, int n_in,
                              void* d_out, int out_size, void* d_ws, size_t ws_size,
                              hipStream_t stream) {
    (void)in_sizes; (void)n_in; (void)out_size; (void)ws_size;
    const float* x      = (const float*)d_in[0];
    const float* w_off  = (const float*)d_in[1];
    const float* b_off  = (const float*)d_in[2];
    const float* w_dcn  = (const float*)d_in[3];
    const float* b_dcn  = (const float*)d_in[4];
    const float* gamma  = (const float*)d_in[5];
    const float* beta   = (const float*)d_in[6];
    const float* mmean  = (const float*)d_in[7];
    const float* mvar   = (const float*)d_in[8];
    float* out = (float*)d_out;

    char* ws = (char*)d_ws;
    u16* xtp    = (u16*)ws;                          // 8,388,608 B
    u16* wT2    = (u16*)(ws + 8388608);              //   589,824 B
    u16* wOffT2 = (u16*)(ws + 8388608 + 589824);     //    73,728 B

    prep_xt  <<<dim3(HW/32, 2), 256, 0, stream>>>(x, xtp);
    prep_wall<<<dim3(9, 288), 128, 0, stream>>>(w_dcn, w_off, wT2, wOffT2);
    dcn_fused<<<dim3(PIX/64), 512, 0, stream>>>(xtp, wT2, wOffT2, b_off, b_dcn,
                                                gamma, beta, mmean, mvar, out);
}

// Round 14
// 63.838 us; speedup vs baseline: 1.1496x; 1.1496x over previous
//
#include <hip/hip_runtime.h>
#include <hip/hip_fp16.h>

#define HH 128
#define WW 128
#define CIN 128
#define COUT 256
#define K9 9
#define HW (HH*WW)          // 16384
#define PIX (2*HW)          // 32768
#define KDIM (CIN*K9)       // 1152
#define BN_EPS 1e-5f

typedef __attribute__((ext_vector_type(8))) short short8;
typedef __attribute__((ext_vector_type(4))) float f32x4;
typedef _Float16 half8 __attribute__((ext_vector_type(8)));
typedef unsigned short u16;
typedef unsigned int u32;

union H8 { short8 s; __half2 h2[4]; half8 h; };

// 16B sampling metadata: 4 clamped hw-indices (u16) + 4 premultiplied bilinear
// weights (f16, mask & validity folded in). Lives in LDS only.
struct __align__(16) Meta16 { ushort4 idx; __half2 w01, w23; };
static_assert(sizeof(Meta16) == 16, "");

__device__ __forceinline__ u16 f2h(float f) {
    union { __half h; u16 u; } x; x.h = __float2half_rn(f); return x.u;
}

// ---------------------------------------------------------------------------
// prep_all: ONE launch for all preprocessing.
//   blocks [0,1024):   x [B][C][HW] f32 -> xt [B][HW][C] f16 (LDS transpose)
//   blocks [1024,2320): wT2[tt][o][32ch], wOffT2[tt][j][32ch] f16 transposes
// ---------------------------------------------------------------------------
__global__ __launch_bounds__(256) void prep_all(
    const float* __restrict__ x, const float* __restrict__ w_dcn,
    const float* __restrict__ w_off, u16* __restrict__ xt,
    u16* __restrict__ wT2, u16* __restrict__ wOffT2)
{
    __shared__ float tile[32][129];
    if (blockIdx.x < 1024) {
        const int b   = blockIdx.x >> 9;
        const int hw0 = (blockIdx.x & 511) * 32;
        const float* __restrict__ xb = x + (size_t)b * (CIN*HW);
        #pragma unroll
        for (int i = 0; i < 16; ++i) {
            const int idx = threadIdx.x + i*256;
            const int c = idx >> 5, hwl = idx & 31;
            tile[hwl][c] = xb[(size_t)c*HW + hw0 + hwl];
        }
        __syncthreads();
        const int hwl = threadIdx.x >> 3;
        const int c0  = (threadIdx.x & 7) * 16;
        short8 s0, s1;
        #pragma unroll
        for (int j = 0; j < 8; ++j) {
            s0[j] = (short)f2h(tile[hwl][c0 + j]);
            s1[j] = (short)f2h(tile[hwl][c0 + 8 + j]);
        }
        u16* dst = xt + ((size_t)b*HW + hw0 + hwl)*CIN + c0;
        *(short8*)dst = s0;
        *(short8*)(dst + 8) = s1;
    } else {
        const int u2 = (blockIdx.x - 1024) * 2 + (threadIdx.x >> 7);  // < 2592
        const int c  = threadIdx.x & 127;
        const int k  = u2 % 9;
        const int o  = u2 / 9;           // 0..287
        const int s = c >> 5, ch = c & 31;
        const int tt = k*4 + s;
        if (o < COUT) {
            wT2[((size_t)tt*COUT + o)*32 + ch] =
                f2h(w_dcn[(size_t)o*KDIM + c*K9 + k]);
        } else {
            const int j = o - COUT;
            wOffT2[((size_t)tt*32 + j)*32 + ch] =
                (j < 27) ? f2h(w_off[(size_t)j*KDIM + c*K9 + k]) : (u16)0;
        }
    }
}

// ---------------------------------------------------------------------------
// dcn_fused: offs-conv (MFMA, meta->LDS) + LDS-staged implicit GEMM.
// 512 threads = 8 waves per block, 64 px per block, 2 blocks/CU.
// Offs phase: wave = 16px x 32j (NO jh duplication of bv), k-loop SPLIT
// across wave pairs (tt 0..17 / 18..35); f32 partials summed via LDS planes.
// Main GEMM: identical to R13 (tied-best): wave wv owns o-slice [wv*32,+32),
// Vs double-buffered, one barrier/phase, FIFO-correct A-first issue order.
// ---------------------------------------------------------------------------
__global__ __launch_bounds__(512, 4) __attribute__((amdgpu_waves_per_eu(4, 4)))
void dcn_fused(
    const u16* __restrict__ xt, const u16* __restrict__ wT2,
    const u16* __restrict__ wOffT2, const float* __restrict__ b_off,
    const float* __restrict__ b_dcn, const float* __restrict__ gamma,
    const float* __restrict__ beta, const float* __restrict__ mmean,
    const float* __restrict__ mvar, float* __restrict__ out)
{
    __shared__ __align__(16) u16 Vs[2][64*128];      // 2 x 16 KB
    __shared__ __align__(16) Meta16 metaL[K9*64];    // 9216 B

    const int t = threadIdx.x, l = t & 63, wv = t >> 6;   // wv 0..7
    const int l15 = l & 15, lq = l >> 4;
    const int bid = (blockIdx.x & 7) * 64 + (blockIdx.x >> 3);  // 512 blocks
    const int pg0 = bid * 64;
    const int b   = pg0 >> 14;
    const int hw0 = pg0 & 16383;
    const u16* __restrict__ xtb = xt + (size_t)b * (HW*CIN);

    // ================= phase -1: offsets conv + meta build =================
    {
        const int pxg = wv & 3;           // px group 0..3 (16 px)
        const int ks  = wv >> 2;          // k-segment: tt in [18ks, 18ks+18)
        const int px  = pxg*16 + l15;     // 0..63
        const int pg  = pg0 + px;
        const int hw  = pg & 16383;
        const int h = hw >> 7, w = hw & 127;
        f32x4 oa0 = {0.f,0.f,0.f,0.f}, oa1 = {0.f,0.f,0.f,0.f};
        #pragma unroll
        for (int it = 0; it < 18; ++it) {
            const int tt = ks*18 + it;
            const int k = tt >> 2, c0 = (tt & 3) * 32;
            const int yy = h + (k/3) - 1, xx = w + (k%3) - 1;
            const bool valid = ((unsigned)yy < HH) && ((unsigned)xx < WW);
            const int idx = min(max(yy,0),HH-1)*WW + min(max(xx,0),WW-1);
            H8 bv, a0, a1;
            bv.s = *(const short8*)(xtb + (size_t)idx*CIN + c0 + lq*8);
            a0.s = *(const short8*)(wOffT2 + ((size_t)tt*32 + l15)*32      + lq*8);
            a1.s = *(const short8*)(wOffT2 + ((size_t)tt*32 + 16 + l15)*32 + lq*8);
            if (!valid) bv.s = (short8){0,0,0,0,0,0,0,0};
            oa0 = __builtin_amdgcn_mfma_f32_16x16x32_f16(a0.h, bv.h, oa0, 0,0,0);
            oa1 = __builtin_amdgcn_mfma_f32_16x16x32_f16(a1.h, bv.h, oa1, 0,0,0);
        }
        // partial sums -> LDS plane[ks] (aliases Vs[ks], [64][33] f32)
        float* plane = (float*)&Vs[ks][0];
        #pragma unroll
        for (int r = 0; r < 4; ++r) {
            plane[px*33 + lq*4 + r]      = oa0[r];
            plane[px*33 + 16 + lq*4 + r] = oa1[r];
        }
        __syncthreads();

        const float* __restrict__ p0 = (const float*)&Vs[0][0];
        const float* __restrict__ p1 = (const float*)&Vs[1][0];
        #pragma unroll
        for (int rd = 0; rd < 2; ++rd) {
            const int u = t + rd*512;
            if (u < 576) {
                const int px2 = u & 63, k = u >> 6;
                const int hwp = (pg0 + px2) & 16383;
                const int hp = hwp >> 7, wp = hwp & 127;
                const float dy = p0[px2*33 + 2*k]     + p1[px2*33 + 2*k]     + b_off[2*k];
                const float dx = p0[px2*33 + 2*k + 1] + p1[px2*33 + 2*k + 1] + b_off[2*k+1];
                const float mm = p0[px2*33 + 18 + k]  + p1[px2*33 + 18 + k]  + b_off[18+k];
                const float py = (float)hp + (float)(k/3) - 1.0f + dy;
                const float px_ = (float)wp + (float)(k%3) - 1.0f + dx;
                const float msk = 1.0f / (1.0f + expf(-mm));
                const float y0f = floorf(py), x0f = floorf(px_);
                const float wy = py - y0f, wx = px_ - x0f;
                const int y0 = (int)y0f, x0 = (int)x0f;
                const int y1 = y0 + 1,   x1 = x0 + 1;
                const bool v00 = ((unsigned)y0 < HH) && ((unsigned)x0 < WW);
                const bool v01 = ((unsigned)y0 < HH) && ((unsigned)x1 < WW);
                const bool v10 = ((unsigned)y1 < HH) && ((unsigned)x0 < WW);
                const bool v11 = ((unsigned)y1 < HH) && ((unsigned)x1 < WW);
                const int y0c = min(max(y0,0),HH-1), y1c = min(max(y1,0),HH-1);
                const int x0c = min(max(x0,0),WW-1), x1c = min(max(x1,0),WW-1);
                Meta16 mo;
                mo.idx.x = (u16)(y0c*WW + x0c);
                mo.idx.y = (u16)(y0c*WW + x1c);
                mo.idx.z = (u16)(y1c*WW + x0c);
                mo.idx.w = (u16)(y1c*WW + x1c);
                const float f00 = v00 ? (1.f-wy)*(1.f-wx)*msk : 0.f;
                const float f01 = v01 ? (1.f-wy)*wx*msk       : 0.f;
                const float f10 = v10 ? wy*(1.f-wx)*msk       : 0.f;
                const float f11 = v11 ? wy*wx*msk             : 0.f;
                mo.w01 = __floats2half2_rn(f00, f01);
                mo.w23 = __floats2half2_rn(f10, f11);
                metaL[k*64 + px2] = mo;
            }
        }
        __syncthreads();   // metaL ready; planes (Vs alias) dead
    }

    // ================= main GEMM (identical to R13) =================
    const int pxl  = t >> 3;           // gather px 0..63
    const int cb   = t & 7;            // gather 16B chunk 0..7
    const int px15 = pxl & 15;

    f32x4 acc[8];                      // acc[m*4+n], m<2, n<4
    #pragma unroll
    for (int i = 0; i < 8; ++i) acc[i] = (f32x4){0.f,0.f,0.f,0.f};

    const u16 *g0, *g1, *g2, *g3;
    __half2 wb0, wb1, wb2, wb3;

#define SETMETA(k_) do { \
    const Meta16 mt_ = metaL[(k_)*64 + pxl]; \
    g0 = xtb + (size_t)mt_.idx.x*CIN + cb*8; \
    g1 = xtb + (size_t)mt_.idx.y*CIN + cb*8; \
    g2 = xtb + (size_t)mt_.idx.z*CIN + cb*8; \
    g3 = xtb + (size_t)mt_.idx.w*CIN + cb*8; \
    wb0 = __half2half2(__low2half(mt_.w01)); \
    wb1 = __half2half2(__high2half(mt_.w01)); \
    wb2 = __half2half2(__low2half(mt_.w23)); \
    wb3 = __half2half2(__high2half(mt_.w23)); \
} while (0)

#define ISSUE(cr_, u_) do { \
    cr_[0].s = *(const short8*)(g0 + (u_)*64); \
    cr_[1].s = *(const short8*)(g1 + (u_)*64); \
    cr_[2].s = *(const short8*)(g2 + (u_)*64); \
    cr_[3].s = *(const short8*)(g3 + (u_)*64); \
} while (0)

#define COMBINE_WRITE(cr_, u_, buf_) do { \
    H8 r_; \
    _Pragma("unroll") \
    for (int i_ = 0; i_ < 4; ++i_) \
        r_.h2[i_] = __hfma2(cr_[3].h2[i_], wb3, __hfma2(cr_[2].h2[i_], wb2, \
                    __hfma2(cr_[1].h2[i_], wb1, __hmul2(cr_[0].h2[i_], wb0)))); \
    *(short8*)&Vs[buf_][pxl*128 + ((cb + (u_)*8) ^ px15)*8] = r_.s; \
} while (0)

    H8 cA[4], cB[4];
    // prologue: gather k=0 -> Vs[0]
    SETMETA(0);
    ISSUE(cA, 0); ISSUE(cB, 1);
    COMBINE_WRITE(cA, 0, 0); COMBINE_WRITE(cB, 1, 0);
    __syncthreads();

    int cur = 0;
    for (int k = 0; k < 9; ++k) {
        const bool pf = (k < 8);
        // A-frags for all 4 subtiles x 2 m-frags FIRST (oldest in VMEM FIFO)
        H8 av[4][2];
        #pragma unroll
        for (int s = 0; s < 4; ++s)
            #pragma unroll
            for (int m = 0; m < 2; ++m)
                av[s][m].s = *(const short8*)
                    (wT2 + ((size_t)(k*4 + s)*COUT + wv*32 + m*16 + l15)*32 + lq*8);
        __builtin_amdgcn_sched_barrier(0);
        if (pf) { SETMETA(k+1); ISSUE(cA, 0); ISSUE(cB, 1); }
        __builtin_amdgcn_sched_barrier(0);

        #pragma unroll
        for (int s = 0; s < 4; ++s) {
            #pragma unroll
            for (int nh = 0; nh < 2; ++nh) {
                H8 bf[2];
                #pragma unroll
                for (int j = 0; j < 2; ++j) {
                    const int n = nh*2 + j;
                    bf[j].s = *(const short8*)
                        &Vs[cur][(n*16 + l15)*128 + ((s*4 + lq) ^ l15)*8];
                }
                #pragma unroll
                for (int m = 0; m < 2; ++m)
                    #pragma unroll
                    for (int j = 0; j < 2; ++j)
                        acc[m*4 + nh*2 + j] =
                            __builtin_amdgcn_mfma_f32_16x16x32_f16(
                                av[s][m].h, bf[j].h, acc[m*4 + nh*2 + j], 0, 0, 0);
            }
        }
        if (pf) { COMBINE_WRITE(cA, 0, cur ^ 1); COMBINE_WRITE(cB, 1, cur ^ 1); }
        __syncthreads();
        cur ^= 1;
    }
#undef SETMETA
#undef ISSUE
#undef COMBINE_WRITE

    // ---- epilogue: bias + BN + ReLU, coalesced stores ----
    #pragma unroll
    for (int m = 0; m < 2; ++m) {
        #pragma unroll
        for (int r = 0; r < 4; ++r) {
            const int o = wv*32 + m*16 + lq*4 + r;
            const float sc = gamma[o] * rsqrtf(mvar[o] + BN_EPS);
            const float sh = (b_dcn[o] - mmean[o]) * sc + beta[o];
            float* __restrict__ op = out + ((size_t)(b*COUT + o) << 14) + hw0;
            #pragma unroll
            for (int n = 0; n < 4; ++n) {
                const float v = fmaf(acc[m*4 + n][r], sc, sh);
                op[n*16 + l15] = fmaxf(v, 0.f);
            }
        }
    }
}

extern "C" void kernel_launch(void* const* d_in, const int* in_sizes, int n_in,
                              void* d_out, int out_size, void* d_ws, size_t ws_size,
                              hipStream_t stream) {
    (void)in_sizes; (void)n_in; (void)out_size; (void)ws_size;
    const float* x      = (const float*)d_in[0];
    const float* w_off  = (const float*)d_in[1];
    const float* b_off  = (const float*)d_in[2];
    const float* w_dcn  = (const float*)d_in[3];
    const float* b_dcn  = (const float*)d_in[4];
    const float* gamma  = (const float*)d_in[5];
    const float* beta   = (const float*)d_in[6];
    const float* mmean  = (const float*)d_in[7];
    const float* mvar   = (const float*)d_in[8];
    float* out = (float*)d_out;

    char* ws = (char*)d_ws;
    u16* xtp    = (u16*)ws;                          // 8,388,608 B
    u16* wT2    = (u16*)(ws + 8388608);              //   589,824 B
    u16* wOffT2 = (u16*)(ws + 8388608 + 589824);     //    73,728 B

    prep_all <<<dim3(1024 + 1296), 256, 0, stream>>>(x, w_dcn, w_off,
                                                     xtp, wT2, wOffT2);
    dcn_fused<<<dim3(PIX/64), 512, 0, stream>>>(xtp, wT2, wOffT2, b_off, b_dcn,
                                                gamma, beta, mmean, mvar, out);
}